// Round 1
// baseline (1415.168 us; speedup 1.0000x reference)
//
#include <hip/hip_runtime.h>
#include <stdint.h>

// RouteCapsule: I=1024 in-caps (D=64), O=32 out-caps (E=64), B=64, 3 routing iters.
// Restructure: materialize u[o,i,b,e] = sum_d x[i,b,d] w[o,i,d,e] ONCE (fp16, 256 MB)
// via bf16-MFMA while also accumulating s0 = (1/32) sum_i u. All three routing
// iterations then run as pure streaming VALU passes over u:
//   logits: L[o,i,b] = sum_e u*v (contiguous dot) + fused softmax over o
//   s-pass: s[o,b,e] = sum_i c*u  (weighted streaming reduction)
// HBM traffic: 512(w) + 256(u wr) + 4*256(u rd) + ~50 MB misc ~= 1.84 GB.

#define IC 1024
#define OC 32
#define DD 64
#define EE 64
#define BB 64

typedef __attribute__((ext_vector_type(8))) short short8;
typedef __attribute__((ext_vector_type(16))) float f32x16;
typedef _Float16 half8 __attribute__((ext_vector_type(8)));

__device__ __forceinline__ unsigned short f2bf(float f) {
    unsigned int u = __float_as_uint(f);
    u = (u + 0x7FFFu + ((u >> 16) & 1u)) >> 16;   // RNE
    return (unsigned short)u;
}
__device__ __forceinline__ unsigned int pk2(float a, float b) {
    return (unsigned int)f2bf(a) | ((unsigned int)f2bf(b) << 16);
}

// ---------------------------------------------------------------------------
// u[o,i,b,e] = sum_d x[i,b,d]*w[o,i,d,e]  (bf16 MFMA, fp32 acc, fp16 store)
// Also s0[o,b,e] += (1/32) sum_i u  (uniform c of iteration 0).
// grid = (ichunk=32, o=32), 256 thr (4 waves), wave = (bh,eh) quadrant of 64x64.
// ---------------------------------------------------------------------------
__global__ __launch_bounds__(256)
void u_gemm_kernel(const float* __restrict__ x,
                   const float* __restrict__ w,
                   _Float16* __restrict__ u,
                   float* __restrict__ s_out)
{
    __shared__ unsigned short xs[64 * 68];   // [b][d] bf16, stride 68
    __shared__ unsigned short wT[64 * 68];   // [e][d] bf16
    const int t = threadIdx.x;
    const int o = blockIdx.y;
    const int chunk = blockIdx.x;
    const int lane = t & 63;
    const int wv = t >> 6;
    const int bh = wv & 1, eh = wv >> 1;
    const int seg = t & 7;
    const int rrow = t >> 3;

    f32x16 stot = (f32x16)0.0f;

    for (int ii = 0; ii < 32; ++ii) {
        const int i = chunk * 32 + ii;
        __syncthreads();
        // stage x rows (fp32 -> bf16), unscaled
        for (int hlf = 0; hlf < 2; ++hlf) {
            const int b = rrow + hlf * 32;
            const float* xp = x + (((size_t)i) * BB + b) * DD + seg * 8;
            const float4 xa = *(const float4*)xp;
            const float4 xb = *(const float4*)(xp + 4);
            uint2* dst = (uint2*)&xs[b * 68 + seg * 8];
            dst[0] = make_uint2(pk2(xa.x, xa.y), pk2(xa.z, xa.w));
            dst[1] = make_uint2(pk2(xb.x, xb.y), pk2(xb.z, xb.w));
        }
        // stage w transposed: thread loads rows d0,d0+1, writes d-pairs per e
        {
            const int d0 = rrow * 2;
            const float* wp = w + ((((size_t)o) * IC + i) * DD + d0) * EE + seg * 8;
            const float4 a0 = *(const float4*)(wp);
            const float4 a1 = *(const float4*)(wp + 4);
            const float4 b0 = *(const float4*)(wp + EE);
            const float4 b1 = *(const float4*)(wp + EE + 4);
            const float r0[8] = {a0.x, a0.y, a0.z, a0.w, a1.x, a1.y, a1.z, a1.w};
            const float r1[8] = {b0.x, b0.y, b0.z, b0.w, b1.x, b1.y, b1.z, b1.w};
            #pragma unroll
            for (int j = 0; j < 8; ++j) {
                const int e = seg * 8 + j;
                *(unsigned int*)&wT[e * 68 + d0] = pk2(r0[j], r1[j]);
            }
        }
        __syncthreads();
        f32x16 acc = (f32x16)0.0f;
        #pragma unroll
        for (int kk = 0; kk < 4; ++kk) {
            const int k0 = kk * 16 + (lane >> 5) * 8;        // d offset
            const int ar = bh * 32 + (lane & 31);            // A row = b
            const int br = eh * 32 + (lane & 31);            // B col = e
            uint2 alo = *(const uint2*)&xs[ar * 68 + k0];
            uint2 ahi = *(const uint2*)&xs[ar * 68 + k0 + 4];
            uint2 blo = *(const uint2*)&wT[br * 68 + k0];
            uint2 bhi = *(const uint2*)&wT[br * 68 + k0 + 4];
            union { uint4 q; short8 s; } au, bu;
            au.q = make_uint4(alo.x, alo.y, ahi.x, ahi.y);
            bu.q = make_uint4(blo.x, blo.y, bhi.x, bhi.y);
            acc = __builtin_amdgcn_mfma_f32_32x32x16_bf16(au.s, bu.s, acc, 0, 0, 0);
        }
        // C layout (m74/m101): col = lane&31, row = (r&3)+8*(r>>2)+4*(lane>>5)
        _Float16* ub = u + ((((size_t)o) * IC + i) * BB) * EE;
        #pragma unroll
        for (int r = 0; r < 16; ++r) {
            const int gb = bh * 32 + (r & 3) + 8 * (r >> 2) + 4 * (lane >> 5);
            const int ge = eh * 32 + (lane & 31);
            ub[gb * EE + ge] = (_Float16)acc[r];
            stot[r] += acc[r];
        }
    }
    #pragma unroll
    for (int r = 0; r < 16; ++r) {
        const int gb = bh * 32 + (r & 3) + 8 * (r >> 2) + 4 * (lane >> 5);
        const int ge = eh * 32 + (lane & 31);
        atomicAdd(&s_out[(((size_t)o) * BB + gb) * EE + ge], stot[r] * (1.0f / 32.0f));
    }
}

// ---------------------------------------------------------------------------
// Per i (grid=1024): L[o,b] = sum_e u[o,i,b,e]*v[o,b,e] (+bprev), softmax over o
// -> c[o,i,b]. FIRST also writes b1 = L. Thread = (b = t>>2, e-quarter = t&3).
// u streams from HBM; v (512 KB fp32) is L2-resident across all blocks.
// ---------------------------------------------------------------------------
template<bool FIRST>
__global__ __launch_bounds__(256)
void logits_kernel(const _Float16* __restrict__ u,
                   const float* __restrict__ v,       // [O][B][E] fp32
                   const float* __restrict__ bprev,   // [O][I][B] (iter2)
                   float* __restrict__ bout,          // [O][I][B] (iter1)
                   float* __restrict__ cbuf)          // [O][I][B]
{
    __shared__ float Lp[OC][BB];
    const int t = threadIdx.x;
    const int i = blockIdx.x;
    const int b = t >> 2;
    const int eq = t & 3;

    for (int o = 0; o < OC; ++o) {
        const _Float16* up = u + ((((size_t)o) * IC + i) * BB + b) * EE + eq * 16;
        const float*    vp = v + (((size_t)o) * BB + b) * EE + eq * 16;
        const half8 u0 = *(const half8*)up;
        const half8 u1 = *(const half8*)(up + 8);
        const float4 va = *(const float4*)vp;
        const float4 vb = *(const float4*)(vp + 4);
        const float4 vc = *(const float4*)(vp + 8);
        const float4 vd = *(const float4*)(vp + 12);
        float p = (float)u0[0]*va.x + (float)u0[1]*va.y + (float)u0[2]*va.z + (float)u0[3]*va.w
                + (float)u0[4]*vb.x + (float)u0[5]*vb.y + (float)u0[6]*vb.z + (float)u0[7]*vb.w
                + (float)u1[0]*vc.x + (float)u1[1]*vc.y + (float)u1[2]*vc.z + (float)u1[3]*vc.w
                + (float)u1[4]*vd.x + (float)u1[5]*vd.y + (float)u1[6]*vd.z + (float)u1[7]*vd.w;
        p += __shfl_xor(p, 1);
        p += __shfl_xor(p, 2);
        if (eq == 0) Lp[o][b] = p;
    }
    __syncthreads();
    if (t < BB) {                              // softmax over o, one thread per b
        const int bb = t;
        float lt[OC];
        float m = -1e30f;
        #pragma unroll
        for (int o = 0; o < OC; ++o) {
            float L = Lp[o][bb];
            if (!FIRST) L += bprev[(((size_t)o) * IC + i) * BB + bb];
            if (FIRST)  bout[(((size_t)o) * IC + i) * BB + bb] = L;
            lt[o] = L;
            m = fmaxf(m, L);
        }
        float Z = 0.f;
        #pragma unroll
        for (int o = 0; o < OC; ++o) { lt[o] = __expf(lt[o] - m); Z += lt[o]; }
        const float rZ = 1.0f / Z;
        #pragma unroll
        for (int o = 0; o < OC; ++o)
            cbuf[(((size_t)o) * IC + i) * BB + bb] = lt[o] * rZ;
    }
}

// ---------------------------------------------------------------------------
// s[o,b,e] += sum_i c[o,i,b] * u[o,i,b,e].  grid = (ichunk=32, o=32).
// Block streams u[o][i0..i0+32][*][*] (256 KB contiguous), accumulates in regs,
// one atomicAdd per output element per block (4.2M total).
// ---------------------------------------------------------------------------
__global__ __launch_bounds__(256)
void sweight_kernel(const _Float16* __restrict__ u,
                    const float* __restrict__ cbuf,
                    float* __restrict__ s_out)
{
    const int t = threadIdx.x;
    const int chunk = blockIdx.x;
    const int o = blockIdx.y;
    const int b = t >> 2;
    const int eq = t & 3;
    float acc[16];
    #pragma unroll
    for (int j = 0; j < 16; ++j) acc[j] = 0.f;
    const int i0 = chunk * 32;
    for (int ii = 0; ii < 32; ++ii) {
        const int i = i0 + ii;
        const float c = cbuf[(((size_t)o) * IC + i) * BB + b];
        const _Float16* up = u + ((((size_t)o) * IC + i) * BB + b) * EE + eq * 16;
        const half8 u0 = *(const half8*)up;
        const half8 u1 = *(const half8*)(up + 8);
        #pragma unroll
        for (int j = 0; j < 8; ++j) acc[j]     += c * (float)u0[j];
        #pragma unroll
        for (int j = 0; j < 8; ++j) acc[8 + j] += c * (float)u1[j];
    }
    float* sp = s_out + (((size_t)o) * BB + b) * EE + eq * 16;
    #pragma unroll
    for (int j = 0; j < 16; ++j) atomicAdd(&sp[j], acc[j]);
}

// v = squash(s): scale = sqrt(|s|^2) / (1 + |s|^2), per [o,b] row of 64. fp32 out.
__global__ __launch_bounds__(256)
void squash_kernel(const float* __restrict__ s, float* __restrict__ vout)
{
    const int o = blockIdx.x;
    const int lane = threadIdx.x & 63;
    const int wv = threadIdx.x >> 6;
    for (int b = wv; b < BB; b += 4) {
        const size_t idx = (((size_t)o) * BB + b) * EE + lane;
        const float val = s[idx];
        float sq = val * val;
        #pragma unroll
        for (int off = 1; off < 64; off <<= 1)
            sq += __shfl_xor(sq, off);
        const float r = sqrtf(sq);
        vout[idx] = val * (r / (1.0f + sq));
    }
}

extern "C" void kernel_launch(void* const* d_in, const int* in_sizes, int n_in,
                              void* d_out, int out_size, void* d_ws, size_t ws_size,
                              hipStream_t stream)
{
    const float* x = (const float*)d_in[0];   // [I][B][D] fp32
    const float* w = (const float*)d_in[1];   // [O][I][D][E] fp32
    float* out = (float*)d_out;               // [O][B][E] fp32

    char* ws = (char*)d_ws;
    float*    s_buf = (float*)ws;                            // 512 KB
    float*    vbuf  = (float*)(ws + (1 << 19));              // 512 KB fp32
    float*    b1    = (float*)(ws + (1 << 20));              // 8 MB
    float*    cbuf  = (float*)(ws + (1 << 20) + (8 << 20));  // 8 MB
    _Float16* u     = (_Float16*)(ws + (17u << 20));         // 256 MB

    const dim3 blk(256);

    // u = x.w (one pass over route_w); s0 = (1/32) sum_i u fused in
    hipMemsetAsync(s_buf, 0, 1 << 19, stream);
    u_gemm_kernel<<<dim3(32, 32), blk, 0, stream>>>(x, w, u, s_buf);
    squash_kernel<<<32, blk, 0, stream>>>(s_buf, vbuf);
    // iter 1: b1 = u.v0, c1 = softmax_o(b1), s1, v1
    logits_kernel<true><<<1024, blk, 0, stream>>>(u, vbuf, nullptr, b1, cbuf);
    hipMemsetAsync(s_buf, 0, 1 << 19, stream);
    sweight_kernel<<<dim3(32, 32), blk, 0, stream>>>(u, cbuf, s_buf);
    squash_kernel<<<32, blk, 0, stream>>>(s_buf, vbuf);
    // iter 2: b2 = b1 + u.v1, c2 = softmax_o(b2), s2, v2 -> out
    logits_kernel<false><<<1024, blk, 0, stream>>>(u, vbuf, b1, nullptr, cbuf);
    hipMemsetAsync(s_buf, 0, 1 << 19, stream);
    sweight_kernel<<<dim3(32, 32), blk, 0, stream>>>(u, cbuf, s_buf);
    squash_kernel<<<32, blk, 0, stream>>>(s_buf, out);
}